// Round 9
// baseline (325.137 us; speedup 1.0000x reference)
//
#include <hip/hip_runtime.h>
#include <hip/hip_bf16.h>

#define IN_DIM 128
#define HH 8
#define DD 16
#define HD 128   // H*D
#define SCAN_B 256
#define CHUNK 8192  // edges per hist/bucketize block

#define MT  64    // nodes per proj block
#define KP  128   // Wt row stride (bf16 elems) — no LDS, no pad needed

typedef float f32x4 __attribute__((ext_vector_type(4)));
typedef short s16x8 __attribute__((ext_vector_type(8)));

// ---------------------------------------------------------------------------
// dtype sniff helper: returns 1 if h is fp32 storage, 0 if bf16.
// ---------------------------------------------------------------------------
__device__ __forceinline__ int sniff_fp32(const unsigned short* h_raw) {
  int sane = 0;
#pragma unroll
  for (int i = 0; i < 128; i += 2) {
    const unsigned short u = h_raw[i];
    const int expo = (u >> 7) & 0xFF;
    if (expo >= 112 && expo <= 143) sane++;
  }
  return (sane >= 40) ? 0 : 1;
}

// ---------------------------------------------------------------------------
// Kernel 1: W^T staging (self-sniffing).  Wt[n][k] bf16, n in [0,384).
// Block 0 publishes the flag and zeroes bucket_size.
// ---------------------------------------------------------------------------
__global__ __launch_bounds__(128) void wt_kernel(
    const unsigned short* __restrict__ h_raw,
    const void* __restrict__ Wq, const void* __restrict__ Wk,
    const void* __restrict__ Wv, __hip_bfloat16* __restrict__ Wt,
    int* __restrict__ flag, int* __restrict__ bucket_size) {
  const int isf = sniff_fp32(h_raw);
  const int n = blockIdx.x;
  const int k = threadIdx.x;
  if (n == 0) {
    if (k == 0) *flag = isf;
    for (int j = k; j < 258; j += 128) bucket_size[j] = 0;
  }
  const int mat = n >> 7;
  const int col = n & 127;
  const void* W = (mat == 0) ? Wq : (mat == 1) ? Wk : Wv;
  float v;
  if (isf) v = ((const float*)W)[(size_t)k * HD + col];
  else     v = __bfloat162float(((const __hip_bfloat16*)W)[(size_t)k * HD + col]);
  Wt[(size_t)n * KP + k] = __float2bfloat16(v);
}

// ---------------------------------------------------------------------------
// Kernel 2 (fused): blocks [0,pgrid) = LDS-FREE MFMA projection; blocks
// [pgrid, pgrid+nchunk) = bucket histogram.
//   Proj: wave w owns nodes node0+w*16+l15.  A-fragments loaded directly
//   from global h (16B bf16 / 2x16B fp32+convert); B-fragments directly
//   from L2-hot Wt.  Zero barriers, zero LDS in this role.
//   Outputs Q/K/V all bf16.
// ---------------------------------------------------------------------------
__global__ __launch_bounds__(256) void proj_hist_kernel(
    const void* __restrict__ h, const __hip_bfloat16* __restrict__ Wt,
    const void* __restrict__ bq, const void* __restrict__ bk,
    const void* __restrict__ bv,
    __hip_bfloat16* __restrict__ Qb, __hip_bfloat16* __restrict__ Kb,
    __hip_bfloat16* __restrict__ Vb,
    const int* __restrict__ flag, int n_nodes,
    const int* __restrict__ dst, int* __restrict__ bucket_size, int n_edges,
    int pgrid) {
  __shared__ int lh[256];  // hist role only (1 KB)

  const int tid = threadIdx.x;

  if (blockIdx.x >= pgrid) {
    const int e0 = (blockIdx.x - pgrid) * CHUNK;
    const int e1 = (e0 + CHUNK < n_edges) ? e0 + CHUNK : n_edges;
    lh[tid] = 0;
    __syncthreads();
    for (int e = e0 + tid; e < e1; e += 256) atomicAdd(&lh[dst[e] >> 8], 1);
    __syncthreads();
    if (lh[tid] > 0) atomicAdd(&bucket_size[tid], lh[tid]);
    return;
  }

  const int node0 = blockIdx.x * MT;
  const int isf = *flag;

  const int wave = tid >> 6;
  const int lane = tid & 63;
  const int l15 = lane & 15;
  const int quad = lane >> 4;

  // ---- A fragments straight from global ----
  const int g = node0 + wave * 16 + l15;
  const int gs = (g < n_nodes) ? g : (n_nodes - 1);  // clamp reads; mask stores
  s16x8 afrag[4];
  if (isf) {
    const float* hp = (const float*)h + (size_t)gs * HD;
#pragma unroll
    for (int k4 = 0; k4 < 4; ++k4) {
      const f32x4 a0 = *(const f32x4*)(hp + k4 * 32 + quad * 8);
      const f32x4 a1 = *(const f32x4*)(hp + k4 * 32 + quad * 8 + 4);
      s16x8 fr;
#pragma unroll
      for (int j = 0; j < 4; ++j) {
        const __hip_bfloat16 b0 = __float2bfloat16(a0[j]);
        const __hip_bfloat16 b1 = __float2bfloat16(a1[j]);
        fr[j] = *(const short*)&b0;
        fr[4 + j] = *(const short*)&b1;
      }
      afrag[k4] = fr;
    }
  } else {
    const __hip_bfloat16* hp = (const __hip_bfloat16*)h + (size_t)gs * HD;
#pragma unroll
    for (int k4 = 0; k4 < 4; ++k4)
      afrag[k4] = *(const s16x8*)(hp + k4 * 32 + quad * 8);
  }

  for (int c = 0; c < 3; ++c) {
    const __hip_bfloat16* wb = Wt + (size_t)c * 128 * KP;

    f32x4 acc[8];
#pragma unroll
    for (int t = 0; t < 8; ++t) acc[t] = (f32x4){0.f, 0.f, 0.f, 0.f};

#pragma unroll
    for (int t = 0; t < 8; ++t) {
#pragma unroll
      for (int k4 = 0; k4 < 4; ++k4) {
        const s16x8 bfrag =
            *(const s16x8*)(wb + (t * 16 + l15) * KP + k4 * 32 + quad * 8);
        acc[t] = __builtin_amdgcn_mfma_f32_16x16x32_bf16(afrag[k4], bfrag,
                                                         acc[t], 0, 0, 0);
      }
    }

    const void* bp = (c == 0) ? bq : (c == 1) ? bk : bv;
    __hip_bfloat16* outp = (c == 0) ? Qb : (c == 1) ? Kb : Vb;
#pragma unroll
    for (int t = 0; t < 8; ++t) {
      const int ncol = t * 16 + l15;
      const float bias = isf ? ((const float*)bp)[ncol]
                             : __bfloat162float(((const __hip_bfloat16*)bp)[ncol]);
#pragma unroll
      for (int r = 0; r < 4; ++r) {
        const int gw = node0 + wave * 16 + quad * 4 + r;
        if (gw < n_nodes)
          outp[(size_t)gw * HD + ncol] = __float2bfloat16(acc[t][r] + bias);
      }
    }
  }
}

// ---------------------------------------------------------------------------
// Bucket scan: exclusive prefix over bucket sizes.
// ---------------------------------------------------------------------------
__global__ __launch_bounds__(256) void bucket_scan_kernel(
    const int* __restrict__ bucket_size, int* __restrict__ bucket_base,
    int* __restrict__ bucket_cur, int nbuck, int n_edges) {
  __shared__ int sh[256];
  const int t = threadIdx.x;
  const int v = (t < nbuck) ? bucket_size[t] : 0;
  sh[t] = v;
  __syncthreads();
  for (int off = 1; off < 256; off <<= 1) {
    int add = (t >= off) ? sh[t - off] : 0;
    __syncthreads();
    sh[t] += add;
    __syncthreads();
  }
  const int excl = sh[t] - v;
  if (t < nbuck) {
    bucket_base[t] = excl;
    bucket_cur[t] = excl;
  }
  if (t == 0) bucket_base[nbuck] = n_edges;
}

// Pass A: block-aggregated bucket scatter.
__global__ __launch_bounds__(256) void bucketize_kernel(
    const int* __restrict__ src, const int* __restrict__ dst,
    int* __restrict__ bucket_cur, unsigned int* __restrict__ ebuf,
    int n_edges) {
  __shared__ int lh[256];
  const int t = threadIdx.x;
  const int e0 = blockIdx.x * CHUNK;
  const int e1 = (e0 + CHUNK < n_edges) ? e0 + CHUNK : n_edges;
  lh[t] = 0;
  __syncthreads();
  for (int e = e0 + t; e < e1; e += 256) atomicAdd(&lh[dst[e] >> 8], 1);
  __syncthreads();
  const int cnt_local = lh[t];
  int base = 0;
  if (cnt_local > 0) base = atomicAdd(&bucket_cur[t], cnt_local);
  __syncthreads();
  lh[t] = base;
  __syncthreads();
  for (int e = e0 + t; e < e1; e += 256) {
    const int d = dst[e];
    const int pos = atomicAdd(&lh[d >> 8], 1);
    ebuf[pos] = ((unsigned int)src[e] << 16) | (unsigned int)d;
  }
}

// Fused pass B: per-bucket count -> LDS scan -> row_ptr -> LDS-cursor scatter.
__global__ __launch_bounds__(256) void bucket_csr_kernel(
    const unsigned int* __restrict__ ebuf, const int* __restrict__ bucket_base,
    int* __restrict__ row_ptr, int* __restrict__ edge_src,
    int n_nodes, int nbuck) {
  __shared__ int lc[256];
  __shared__ int sh[256];
  const int b = blockIdx.x;
  const int t = threadIdx.x;
  const int lo = bucket_base[b], hi = bucket_base[b + 1];
  const int nbase = b << 8;

  lc[t] = 0;
  __syncthreads();
  for (int i = lo + t; i < hi; i += 256)
    atomicAdd(&lc[(ebuf[i] & 0xFFFFu) - nbase], 1);
  __syncthreads();

  const int v = lc[t];
  sh[t] = v;
  __syncthreads();
  for (int off = 1; off < 256; off <<= 1) {
    int add = (t >= off) ? sh[t - off] : 0;
    __syncthreads();
    sh[t] += add;
    __syncthreads();
  }
  const int excl = sh[t] - v;

  const int node = nbase + t;
  if (node < n_nodes) row_ptr[node] = lo + excl;
  if (b == nbuck - 1 && t == 255) row_ptr[n_nodes] = hi;

  __syncthreads();
  lc[t] = lo + excl;
  __syncthreads();
  for (int i = lo + t; i < hi; i += 256) {
    const unsigned int pkd = ebuf[i];
    const int pos = atomicAdd(&lc[(pkd & 0xFFFFu) - nbase], 1);
    edge_src[pos] = (int)(pkd >> 16);
  }
}

// ---------------------------------------------------------------------------
// Fallback CSR build (n_nodes > 65536).
// ---------------------------------------------------------------------------
__global__ __launch_bounds__(256) void hist_kernel(
    const int* __restrict__ dst, int* __restrict__ cnt, int n_edges) {
  const int e = blockIdx.x * blockDim.x + threadIdx.x;
  if (e < n_edges) atomicAdd(&cnt[dst[e]], 1);
}

__global__ __launch_bounds__(256) void scatter_kernel(
    const int* __restrict__ src, const int* __restrict__ dst,
    int* __restrict__ cursor, int* __restrict__ edge_src, int n_edges) {
  const int e = blockIdx.x * blockDim.x + threadIdx.x;
  if (e < n_edges) {
    const int pos = atomicAdd(&cursor[dst[e]], 1);
    edge_src[pos] = src[e];
  }
}

__global__ __launch_bounds__(SCAN_B) void scan1_kernel(
    const int* __restrict__ cnt, int* __restrict__ exs,
    int* __restrict__ bsum, int n) {
  __shared__ int sh[SCAN_B];
  const int t = threadIdx.x;
  const int i = blockIdx.x * SCAN_B + t;
  int v = (i < n) ? cnt[i] : 0;
  sh[t] = v;
  __syncthreads();
  for (int off = 1; off < SCAN_B; off <<= 1) {
    int add = (t >= off) ? sh[t - off] : 0;
    __syncthreads();
    sh[t] += add;
    __syncthreads();
  }
  if (i < n) exs[i] = sh[t] - v;
  if (t == SCAN_B - 1) bsum[blockIdx.x] = sh[t];
}

__global__ __launch_bounds__(SCAN_B) void scan2_kernel(int* __restrict__ bsum,
                                                       int nb) {
  __shared__ int sh[SCAN_B];
  const int t = threadIdx.x;
  if (nb <= SCAN_B) {
    int v = (t < nb) ? bsum[t] : 0;
    sh[t] = v;
    __syncthreads();
    for (int off = 1; off < SCAN_B; off <<= 1) {
      int add = (t >= off) ? sh[t - off] : 0;
      __syncthreads();
      sh[t] += add;
      __syncthreads();
    }
    if (t < nb) bsum[t] = sh[t] - v;
  } else if (t == 0) {
    int run = 0;
    for (int b = 0; b < nb; ++b) { int v = bsum[b]; bsum[b] = run; run += v; }
  }
}

__global__ __launch_bounds__(SCAN_B) void scan3_kernel(
    const int* __restrict__ exs, const int* __restrict__ bsum,
    int* __restrict__ row_ptr, int* __restrict__ cursor, int n, int n_edges) {
  const int i = blockIdx.x * SCAN_B + threadIdx.x;
  if (i < n) {
    const int v = exs[i] + bsum[blockIdx.x];
    row_ptr[i] = v;
    cursor[i] = v;
  }
  if (i == 0) row_ptr[n] = n_edges;
}

// ---------------------------------------------------------------------------
// Kernel 3: per-destination gather (round-8 structure; Q now bf16).
// ---------------------------------------------------------------------------
__global__ __launch_bounds__(128) void gather_kernel(
    const int* __restrict__ row_ptr, const int* __restrict__ edge_src,
    const __hip_bfloat16* __restrict__ Qb, const __hip_bfloat16* __restrict__ Kb,
    const __hip_bfloat16* __restrict__ Vb,
    void* __restrict__ out, const int* __restrict__ flag, int n_nodes) {
  __shared__ float2 sc[2][16 * HH];  // (score, src-bits) per (edge, head)
  __shared__ float zred[16 * HH];

  const int d = blockIdx.x;
  const int tid = threadIdx.x;

  const int eloc = tid >> 3;
  const int hh8  = tid & 7;
  const int hd16 = tid >> 4;

  const int start = row_ptr[d];
  const int deg = row_ptr[d + 1] - start;

  // Q slice (16 bf16 ch of head hh8), pre-scaled by 1/sqrt(D)=0.25
  float qreg[16];
  {
    const uint4* qp = (const uint4*)(Qb + (size_t)d * HD + hh8 * 16);
    unsigned int qw[8];
    *(uint4*)&qw[0] = qp[0];
    *(uint4*)&qw[4] = qp[1];
#pragma unroll
    for (int i = 0; i < 8; ++i) {
      qreg[2 * i]     = __uint_as_float(qw[i] << 16) * 0.25f;
      qreg[2 * i + 1] = __uint_as_float(qw[i] & 0xFFFF0000u) * 0.25f;
    }
  }

  float accV = 0.0f;
  float zacc = 0.0f;
  const int ngroups = (deg + 15) >> 4;

  for (int g = 0; g < ngroups; ++g) {
    const int buf = g & 1;
    const int ei = g * 16 + eloc;

    float score = 0.0f;
    int s = 0;
    if (ei < deg) {
      s = edge_src[start + ei];
      const uint4* kp = (const uint4*)(Kb + (size_t)s * HD + hh8 * 16);
      unsigned int kw[8];
      *(uint4*)&kw[0] = kp[0];
      *(uint4*)&kw[4] = kp[1];
      float dot = 0.0f;
#pragma unroll
      for (int i = 0; i < 8; ++i) {
        const float klo = __uint_as_float(kw[i] << 16);
        const float khi = __uint_as_float(kw[i] & 0xFFFF0000u);
        dot = fmaf(qreg[2 * i], klo, dot);
        dot = fmaf(qreg[2 * i + 1], khi, dot);
      }
      score = __expf(fminf(fmaxf(dot, -5.0f), 5.0f));
    }
    zacc += score;
    sc[buf][eloc * HH + hh8] = make_float2(score, __int_as_float(s));
    __syncthreads();

    const int rem = deg - g * 16;
    const int lim = (rem < 16) ? rem : 16;
    if (lim == 16) {
#pragma unroll
      for (int e = 0; e < 16; ++e) {
        const float2 pe = sc[buf][e * HH + hd16];
        const int s2 = __float_as_int(pe.y);
        const unsigned short vu =
            *(const unsigned short*)(Vb + (size_t)s2 * HD + tid);
        accV = fmaf(pe.x, __uint_as_float(((unsigned int)vu) << 16), accV);
      }
    } else {
      for (int e = 0; e < lim; ++e) {
        const float2 pe = sc[buf][e * HH + hd16];
        const int s2 = __float_as_int(pe.y);
        const unsigned short vu =
            *(const unsigned short*)(Vb + (size_t)s2 * HD + tid);
        accV = fmaf(pe.x, __uint_as_float(((unsigned int)vu) << 16), accV);
      }
    }
  }

  zred[eloc * HH + hh8] = zacc;
  __syncthreads();
  float aZ = 0.0f;
#pragma unroll
  for (int i = 0; i < 16; ++i) aZ += zred[i * HH + hd16];

  const float r = accV / (aZ + 1e-6f);
  const size_t o = (size_t)d * HD + tid;
  if (*flag) ((float*)out)[o] = r;
  else       ((__hip_bfloat16*)out)[o] = __float2bfloat16(r);
}

// ---------------------------------------------------------------------------
extern "C" void kernel_launch(void* const* d_in, const int* in_sizes, int n_in,
                              void* d_out, int out_size, void* d_ws, size_t ws_size,
                              hipStream_t stream) {
  const void* h  = d_in[0];
  const void* Wq = d_in[1];
  const void* bq = d_in[2];
  const void* Wk = d_in[3];
  const void* bk = d_in[4];
  const void* Wv = d_in[5];
  const void* bv = d_in[6];
  const int* src = (const int*)d_in[7];
  const int* dst = (const int*)d_in[8];

  const int n_nodes = in_sizes[0] / IN_DIM;  // 50000
  const int n_edges = in_sizes[7];           // 1600000
  const int nb = (n_nodes + SCAN_B - 1) / SCAN_B;
  const int nbuck = (n_nodes + 255) >> 8;

  // workspace layout (256B-aligned chunks)
  char* p = (char*)d_ws;
  int* flag = (int*)p;                       p += 256;
  __hip_bfloat16* Qb = (__hip_bfloat16*)p;   p += (size_t)n_nodes * HD * 2;
  __hip_bfloat16* Kb = (__hip_bfloat16*)p;   p += (size_t)n_nodes * HD * 2;
  __hip_bfloat16* Vb = (__hip_bfloat16*)p;   p += (size_t)n_nodes * HD * 2;
  __hip_bfloat16* Wt = (__hip_bfloat16*)p;   p += ((size_t)384 * KP * 2 + 255) / 256 * 256;
  int* bucket_size = (int*)p;                p += 258 * 4;
  int* bucket_base = (int*)p;                p += 258 * 4;
  int* bucket_cur = (int*)p;                 p += 258 * 4;
  int* row_ptr = (int*)p;                    p += (size_t)(n_nodes + 1) * 4;
  unsigned int* ebuf = (unsigned int*)p;     p += (size_t)n_edges * 4;
  int* edge_src = (int*)p;                   p += (size_t)n_edges * 4;
  // fallback-only arrays
  int* cnt = (int*)p;                        p += (size_t)n_nodes * 4;
  int* exs = (int*)p;                        p += (size_t)n_nodes * 4;
  int* bsum = (int*)p;                       p += (size_t)(nb + 1) * 4;
  int* cursor = (int*)p;                     p += (size_t)n_nodes * 4;

  wt_kernel<<<384, 128, 0, stream>>>((const unsigned short*)h, Wq, Wk, Wv, Wt,
                                     flag, bucket_size);

  const int pgrid = (n_nodes + MT - 1) / MT;
  const int nchunk = (n_edges + CHUNK - 1) / CHUNK;

  if (n_nodes <= 65536) {
    proj_hist_kernel<<<pgrid + nchunk, 256, 0, stream>>>(
        h, Wt, bq, bk, bv, Qb, Kb, Vb, flag, n_nodes, dst, bucket_size,
        n_edges, pgrid);
    bucket_scan_kernel<<<1, 256, 0, stream>>>(bucket_size, bucket_base,
                                              bucket_cur, nbuck, n_edges);
    bucketize_kernel<<<nchunk, 256, 0, stream>>>(src, dst, bucket_cur, ebuf,
                                                 n_edges);
    bucket_csr_kernel<<<nbuck, 256, 0, stream>>>(ebuf, bucket_base, row_ptr,
                                                 edge_src, n_nodes, nbuck);
  } else {
    proj_hist_kernel<<<pgrid, 256, 0, stream>>>(
        h, Wt, bq, bk, bv, Qb, Kb, Vb, flag, n_nodes, dst, bucket_size,
        n_edges, pgrid);
    hipMemsetAsync(cnt, 0, (size_t)n_nodes * sizeof(int), stream);
    const int eb = 256;
    const int egrid = (n_edges + eb - 1) / eb;
    hist_kernel<<<egrid, eb, 0, stream>>>(dst, cnt, n_edges);
    scan1_kernel<<<nb, SCAN_B, 0, stream>>>(cnt, exs, bsum, n_nodes);
    scan2_kernel<<<1, SCAN_B, 0, stream>>>(bsum, nb);
    scan3_kernel<<<nb, SCAN_B, 0, stream>>>(exs, bsum, row_ptr, cursor,
                                            n_nodes, n_edges);
    scatter_kernel<<<egrid, eb, 0, stream>>>(src, dst, cursor, edge_src,
                                             n_edges);
  }

  gather_kernel<<<n_nodes, 128, 0, stream>>>(row_ptr, edge_src, Qb, Kb, Vb,
                                             d_out, flag, n_nodes);
}